// Round 10
// baseline (397.814 us; speedup 1.0000x reference)
//
#include <hip/hip_runtime.h>
#include <math.h>

#define HW 320
#define IMGSZ (HW*HW)
#define NB 4

typedef __bf16 bf16x8 __attribute__((ext_vector_type(8)));
typedef float  f32x4  __attribute__((ext_vector_type(4)));

__device__ __forceinline__ float4 ld4(const float* p){ return *reinterpret_cast<const float4*>(p); }

__device__ __forceinline__ unsigned short f2b(float f){
  unsigned u = __float_as_uint(f);
  unsigned r = (u + 0x7fffu + ((u>>16)&1u)) >> 16;
  return (unsigned short)r;
}

// u = x + xi*(x - xprev)
__global__ void ew_u(const float* __restrict__ x, const float* __restrict__ xprev,
                     const float* __restrict__ t_p, float* __restrict__ u, int n4){
  int i = blockIdx.x*blockDim.x + threadIdx.x;
  if (i >= n4) return;
  float t = *t_p;
  float tplus = (1.f + sqrtf(1.f + 4.f*t*t)) * 0.5f;
  float xi = (t - 1.f)/tplus;
  float4 xv = ld4(x + 4*i); float4 pv = ld4(xprev + 4*i);
  float4 r;
  r.x = xv.x + xi*(xv.x-pv.x);
  r.y = xv.y + xi*(xv.y-pv.y);
  r.z = xv.z + xi*(xv.z-pv.z);
  r.w = xv.w + xi*(xv.w-pv.w);
  *reinterpret_cast<float4*>(u + 4*i) = r;
}

// ---------------------------------------------------------------------------
// Phi path as split-bf16 MFMA GEMMs (hi/lo fp32 emulation, AhBh+AhBl+AlBh).
// ---------------------------------------------------------------------------

// PhiW(256,3,32,32) -> PhiB[c][mt4][ks32][nf4][hilo2][lane64] uint4
__global__ void pack_phib(const float* __restrict__ PhiW, uint4* __restrict__ PhiB){
  int idx = blockIdx.x*256 + threadIdx.x;   // 98304 total
  int lane = idx & 63;
  int t2 = idx >> 6;                        // ((c*4+mt)*32+ks)*4+nf
  int nf = t2 & 3, ks = (t2>>2)&31, cm = t2>>7;
  int m = (cm&3)*64 + nf*16 + (lane&15);
  int c = cm>>2;
  int kbase = ks*32 + (lane>>4)*8;
  const float* src = PhiW + ((size_t)m*3 + c)*1024 + kbase;
  float4 v0 = ld4(src), v1 = ld4(src+4);
  float vals[8] = {v0.x,v0.y,v0.z,v0.w,v1.x,v1.y,v1.z,v1.w};
  uint4 hi, lo; unsigned* hw = (unsigned*)&hi; unsigned* lw = (unsigned*)&lo;
  #pragma unroll
  for (int p=0;p<4;p++){
    unsigned h0 = f2b(vals[2*p]), h1 = f2b(vals[2*p+1]);
    float r0 = vals[2*p]   - __uint_as_float(h0<<16);
    float r1 = vals[2*p+1] - __uint_as_float(h1<<16);
    hw[p] = h0 | (h1<<16);
    lw[p] = (unsigned)f2b(r0) | ((unsigned)f2b(r1)<<16);
  }
  PhiB[(size_t)t2*128 + lane] = hi;
  PhiB[(size_t)t2*128 + 64 + lane] = lo;
}

// PhiTW(3*1024,256,1,1) -> PhiTB[c][n64x16][ks8][nf4][hilo2][lane64] uint4
__global__ void pack_phitb(const float* __restrict__ PhiTW, uint4* __restrict__ PhiTB){
  int idx = blockIdx.x*256 + threadIdx.x;   // 98304 total
  int lane = idx & 63;
  int t2 = idx >> 6;                        // ((c*16+n64)*8+ks)*4+nf
  int nf = t2 & 3, ks = (t2>>2)&7, cn = t2>>5;
  int n = (cn&15)*64 + nf*16 + (lane&15);
  int c = cn>>4;
  int kbase = ks*32 + (lane>>4)*8;
  const float* src = PhiTW + ((size_t)c*1024 + n)*256 + kbase;
  float4 v0 = ld4(src), v1 = ld4(src+4);
  float vals[8] = {v0.x,v0.y,v0.z,v0.w,v1.x,v1.y,v1.z,v1.w};
  uint4 hi, lo; unsigned* hw = (unsigned*)&hi; unsigned* lw = (unsigned*)&lo;
  #pragma unroll
  for (int p=0;p<4;p++){
    unsigned h0 = f2b(vals[2*p]), h1 = f2b(vals[2*p+1]);
    float r0 = vals[2*p]   - __uint_as_float(h0<<16);
    float r1 = vals[2*p+1] - __uint_as_float(h1<<16);
    hw[p] = h0 | (h1<<16);
    lw[p] = (unsigned)f2b(r0) | ((unsigned)f2b(r1)<<16);
  }
  PhiTB[(size_t)t2*128 + lane] = hi;
  PhiTB[(size_t)t2*128 + 64 + lane] = lo;
}

// grid(25 rowtiles, 4 mtiles, 3 c) x 256.  Waves K-split (256 k each), LDS reduce.
__global__ __launch_bounds__(256)
void phi_gemm(const float* __restrict__ u, const uint4* __restrict__ PhiB,
              uint4* __restrict__ PhA){
  __shared__ uint4 As[2][2048];   // [hilo][kb*16+m], 64 KB
  const int rt = blockIdx.x, mt = blockIdx.y, c = blockIdx.z;
  const int tid = threadIdx.x, lane = tid & 63, w = tid >> 6;

  for (int idx = tid; idx < 4096; idx += 256){
    int m = idx >> 8;
    int f4 = idx & 255;
    int k = f4*4;
    int r = rt*16 + m;
    int b = r/100, blk = r - b*100;
    int bh = blk/10, bw = blk - bh*10;
    int ip = k >> 5, jp = k & 31;
    float4 v = ld4(u + ((size_t)((b*3+c)*HW + bh*32+ip))*HW + bw*32 + jp);
    float vv[4] = {v.x,v.y,v.z,v.w};
    unsigned hh[4], ll[4];
    #pragma unroll
    for (int e=0;e<4;e++){
      hh[e] = f2b(vv[e]);
      ll[e] = f2b(vv[e] - __uint_as_float(hh[e]<<16));
    }
    int kb = k >> 3, off = (k & 7) ? 1 : 0;
    ((uint2*)&As[0][kb*16+m])[off] = make_uint2(hh[0]|(hh[1]<<16), hh[2]|(hh[3]<<16));
    ((uint2*)&As[1][kb*16+m])[off] = make_uint2(ll[0]|(ll[1]<<16), ll[2]|(ll[3]<<16));
  }
  __syncthreads();

  f32x4 acc[4] = {};
  const uint4* bbase = PhiB + (size_t)(c*4+mt)*32*512;
  for (int ksl = 0; ksl < 8; ++ksl){
    int ks = w*8 + ksl;
    bf16x8 ah = __builtin_bit_cast(bf16x8, As[0][ks*64 + lane]);
    bf16x8 al = __builtin_bit_cast(bf16x8, As[1][ks*64 + lane]);
    #pragma unroll
    for (int nf=0; nf<4; ++nf){
      const uint4* bp = bbase + ((size_t)ks*4 + nf)*128;
      bf16x8 bh = __builtin_bit_cast(bf16x8, bp[lane]);
      bf16x8 bl = __builtin_bit_cast(bf16x8, bp[64 + lane]);
      acc[nf] = __builtin_amdgcn_mfma_f32_16x16x32_bf16(ah, bh, acc[nf], 0,0,0);
      acc[nf] = __builtin_amdgcn_mfma_f32_16x16x32_bf16(ah, bl, acc[nf], 0,0,0);
      acc[nf] = __builtin_amdgcn_mfma_f32_16x16x32_bf16(al, bh, acc[nf], 0,0,0);
    }
  }

  __syncthreads();
  float* rf = (float*)As;
  #pragma unroll
  for (int nf=0; nf<4; ++nf)
    ((float4*)rf)[(w*64+lane)*4 + nf] = *(float4*)&acc[nf];
  __syncthreads();

  int o = tid*4;
  int i = o >> 6, j = o & 63;
  int nf = j >> 4, q = i >> 2, reg = i & 3;
  unsigned hh[4], ll[4];
  #pragma unroll
  for (int e=0;e<4;e++){
    int ls = q*16 + (j&15) + e;
    float v = rf[(0*64+ls)*16 + nf*4+reg] + rf[(1*64+ls)*16 + nf*4+reg]
            + rf[(2*64+ls)*16 + nf*4+reg] + rf[(3*64+ls)*16 + nf*4+reg];
    hh[e] = f2b(v);
    ll[e] = f2b(v - __uint_as_float(hh[e]<<16));
  }
  int kb = mt*8 + (j>>3);
  int off = (j & 7) ? 1 : 0;
  ((uint2*)&PhA[((size_t)(0*3+c)*25 + rt)*512 + kb*16 + i])[off] =
      make_uint2(hh[0]|(hh[1]<<16), hh[2]|(hh[3]<<16));
  ((uint2*)&PhA[((size_t)(1*3+c)*25 + rt)*512 + kb*16 + i])[off] =
      make_uint2(ll[0]|(ll[1]<<16), ll[2]|(ll[3]<<16));
}

// grid(25 rowtiles, 4 ntiles-of-256, 3 c) x 256.  Waves split N (64 each).
__global__ __launch_bounds__(256)
void phit_gemm(const uint4* __restrict__ PhA, const uint4* __restrict__ PhiTB,
               const float* __restrict__ u, const float* __restrict__ PhiTb,
               const float* __restrict__ lam_p, float* __restrict__ x_input){
  const int rt = blockIdx.x, nt4 = blockIdx.y, c = blockIdx.z;
  const int tid = threadIdx.x, lane = tid & 63, w = tid >> 6;
  f32x4 acc[4] = {};
  const uint4* ah_base = PhA + ((size_t)(0*3+c)*25 + rt)*512;
  const uint4* al_base = PhA + ((size_t)(1*3+c)*25 + rt)*512;
  const uint4* bbase = PhiTB + (size_t)(c*16 + nt4*4 + w)*8*512;
  #pragma unroll
  for (int ks=0; ks<8; ++ks){
    bf16x8 ah = __builtin_bit_cast(bf16x8, ah_base[ks*64 + lane]);
    bf16x8 al = __builtin_bit_cast(bf16x8, al_base[ks*64 + lane]);
    #pragma unroll
    for (int nf=0; nf<4; ++nf){
      const uint4* bp = bbase + ((size_t)ks*4 + nf)*128;
      bf16x8 bh = __builtin_bit_cast(bf16x8, bp[lane]);
      bf16x8 bl = __builtin_bit_cast(bf16x8, bp[64 + lane]);
      acc[nf] = __builtin_amdgcn_mfma_f32_16x16x32_bf16(ah, bh, acc[nf], 0,0,0);
      acc[nf] = __builtin_amdgcn_mfma_f32_16x16x32_bf16(ah, bl, acc[nf], 0,0,0);
      acc[nf] = __builtin_amdgcn_mfma_f32_16x16x32_bf16(al, bh, acc[nf], 0,0,0);
    }
  }
  float lam = *lam_p;
  int q = lane >> 4, jl = lane & 15;
  #pragma unroll
  for (int nf=0; nf<4; ++nf){
    int n = nt4*256 + w*64 + nf*16 + jl;
    int ip = n >> 5, jp = n & 31;
    #pragma unroll
    for (int reg=0; reg<4; ++reg){
      int r = rt*16 + q*4 + reg;
      int b = r/100, blk = r - b*100;
      int bh_ = blk/10, bw_ = blk - bh_*10;
      size_t g = ((size_t)((b*3+c)*HW + bh_*32+ip))*HW + bw_*32 + jp;
      x_input[g] = u[g] - lam*acc[nf][reg] + lam*PhiTb[g];
    }
  }
}

// ---------------------------------------------------------------------------
// convD fused: 3x3 conv (3ch -> 32oc) from fp32 NCHW directly to blocked bf16.
// ---------------------------------------------------------------------------
__global__ __launch_bounds__(256)
void conv_direct_blocked(const float* __restrict__ in, const float* __restrict__ wts,
                         uint4* __restrict__ dst){
  const int tile = blockIdx.x, g = blockIdx.y, b = blockIdx.z;
  const int x0 = (tile % 20)*16, y0 = (tile / 20)*16;
  const int tid = threadIdx.x;
  __shared__ float ism[3*18*20];
  __shared__ float wsm[8*27];
  for (int i = tid; i < 3*18*18; i += 256){
    int ic = i / 324; int rr = i - ic*324; int r = rr/18, c = rr - r*18;
    int gy = y0 - 1 + r, gx = x0 - 1 + c;
    float v = 0.f;
    if (gy>=0 && gy<HW && gx>=0 && gx<HW)
      v = in[(size_t)(b*3+ic)*IMGSZ + (size_t)gy*HW + gx];
    ism[(ic*18+r)*20 + c] = v;
  }
  if (tid < 216) wsm[tid] = wts[(size_t)(g*8 + tid/27)*27 + (tid%27)];
  __syncthreads();

  const int px = tid & 15, py = tid >> 4;
  float acc[8] = {};
  #pragma unroll
  for (int ic=0; ic<3; ++ic)
    #pragma unroll
    for (int ky=0; ky<3; ++ky)
      #pragma unroll
      for (int kx=0; kx<3; ++kx){
        float v = ism[(ic*18+py+ky)*20 + px+kx];
        #pragma unroll
        for (int o=0;o<8;o++)
          acc[o] += wsm[o*27 + ic*9 + ky*3 + kx] * v;
      }
  uint4 ov; unsigned* ow = (unsigned*)&ov;
  #pragma unroll
  for (int p=0;p<4;p++)
    ow[p] = (unsigned)f2b(acc[2*p]) | ((unsigned)f2b(acc[2*p+1])<<16);
  dst[(((size_t)(b*4+g)*HW + (y0+py))*HW + x0+px)] = ov;
}

// ---------------------------------------------------------------------------
// Weight packing with meta folded in — parallel meta loads.
// pres[set] encoding: bit (d-1)*2 + h set iff dilation class d has >=1 output
// channel in oc-half h (after the counting sort, classes are oc-contiguous).
// ---------------------------------------------------------------------------
__global__ void pack_w(const float* w0,const float* w1,const float* w2,
                       const float* w3,const float* w4,const float* w5,
                       const float* w6,
                       const float* p0,const float* p1,const float* p2,
                       const float* p3,const float* p4,const float* p5,
                       int* __restrict__ pres, uint4* __restrict__ wp){
  const float* wsel[7] = {w0,w1,w2,w3,w4,w5,w6};
  const float* psel[6] = {p0,p1,p2,p3,p4,p5};
  const int set_of[13]  = {0,1,1,1,2,3,3,3,4,5,5,5,6};
  const int cls_of[13]  = {1,1,2,3,1,1,2,3,1,1,2,3,1};
  const int Ts[6] = {1,3,1,3,1,3};
  int slot = blockIdx.x;
  int set = set_of[slot], cls = cls_of[slot];

  __shared__ int   s_idx[32];
  __shared__ float s_mx[32];
  __shared__ int   s_src[32];
  __shared__ int   s_d[32];
  __shared__ float s_scale[32];

  if (set < 6 && threadIdx.x < 32){
    const float* para = psel[set];
    int T = Ts[set];
    int c = threadIdx.x;
    int best = 0; float bv = para[c*T];
    for (int t=1;t<T;t++){ float v = para[c*T+t]; if (v>bv){bv=v;best=t;} }
    s_idx[c] = best; s_mx[c] = bv;
  }
  __syncthreads();

  if (set < 6 && threadIdx.x == 0){
    float sum[3]={0.f,0.f,0.f}; int cnt[3]={0,0,0};
    for (int c=0;c<32;c++){ sum[s_idx[c]] += s_mx[c]; cnt[s_idx[c]]++; }
    float mul[3];
    for (int t=0;t<3;t++) mul[t] = sum[t]/fmaxf((float)cnt[t],1.f)+1.f;
    int off[3]; off[0]=0; off[1]=cnt[0]; off[2]=cnt[0]+cnt[1];
    int perm[32];
    for (int c=0;c<32;c++) perm[off[s_idx[c]]++] = c;   // stable counting sort
    int pb = 0;
    for (int k=0;k<32;k++){
      int s = perm[k];
      s_src[k]=s; s_d[k]=s_idx[s]+1; s_scale[k]=mul[s_idx[s]];
      pb |= 1 << ((s_idx[s])*2 + (k>>4));   // (d-1)*2 + half
    }
    if (cls == 1) pres[set] = pb;
  }
  __syncthreads();

  const float* W = wsel[set];
  unsigned short* out = (unsigned short*)(wp + (size_t)slot*1152);
  for (int v = threadIdx.x; v < 9216; v += 256){
    int j = v & 7;
    int lane = (v >> 3) & 63;
    int rest = v >> 9;           // h*9+t
    int t = rest % 9, h = rest / 9;
    int ocl = lane & 15, q = lane >> 4;
    int oc = h*16 + ocl;
    int ic = q*8 + j;
    float val = 0.f;
    if (set == 6){
      if (oc < 3) val = W[(size_t)oc*(32*9) + ic*9 + t];
    } else {
      if (s_d[oc] == cls){
        int src = s_src[oc];
        val = W[(size_t)src*(32*9) + ic*9 + t] * s_scale[oc];
      }
    }
    out[v] = f2b(val);
  }
}

// ---------------------------------------------------------------------------
// MFMA conv body. Block 256thr=4 waves; block tile 32 x ROWS; wave: ROWS/4 rows.
// ROWS=8, full-batch reg staging, B-frag next-tap prefetch.
// NPASS==3: per-(dilation, oc-half) presence gating — skips MFMA passes whose
// packed weights are all zero (classes are oc-contiguous after sort).
// EPI: 0 none / 1 relu (blocked bf16 out via LDS transpose)
//      2 merge: out0 fp32 = epi + ms*acc (oc<3)
//      3 sub:   out1 fp32 = acc - bf16(epi blocked), via fp32 LDS transpose
// ---------------------------------------------------------------------------
template<int H,int NPASS,int NH,int ROWS,int ITRANS,int EPI>
__device__ __forceinline__ void conv_body(char* smem,
    const uint4* __restrict__ inb, const uint4* __restrict__ wp,
    void* __restrict__ outp, const int* __restrict__ pres_p, int set,
    const float* __restrict__ thr_p, const float* __restrict__ epi_ptr,
    const float* __restrict__ ms_p, int tx, int ty, int b){
  constexpr int TW = 32 + 2*H, TH = ROWS + 2*H, TP = TW*TH;
  constexpr int RPW = ROWS/4;          // rows per wave
  constexpr int MT  = ROWS/2;          // mfma tiles per wave
  constexpr int PW  = ROWS*8;          // pixels per wave

  const int x0 = tx*32, y0 = ty*ROWS;
  const int tid = threadIdx.x;
  const int lane = tid & 63, w = tid >> 6;
  const int m = lane & 15, q = lane >> 4;

  // ---- stage input tile: full-batch loads, then transform + LDS write ----
  float thr = (ITRANS==2) ? *thr_p : 0.f;
  uint4* sm16 = (uint4*)smem;
  constexpr int TOT = 4*TP;
  constexpr int NSTG = (TOT + 255)/256;
  {
    uint4 v[NSTG];
    #pragma unroll
    for (int uu=0; uu<NSTG; ++uu){
      v[uu] = make_uint4(0,0,0,0);
      int i = tid + uu*256;
      if (i < TOT){
        int g = i / TP; int rr = i - g*TP; int r = rr / TW; int c = rr - r*TW;
        int gy = y0 - H + r, gx = x0 - H + c;
        if (gy>=0 && gy<HW && gx>=0 && gx<HW)
          v[uu] = inb[(((size_t)(b*4+g)*HW + gy)*HW + gx)];
      }
    }
    #pragma unroll
    for (int uu=0; uu<NSTG; ++uu){
      int i = tid + uu*256;
      if (i < TOT){
        uint4 vv = v[uu];
        if (ITRANS==1){
          unsigned* pw = (unsigned*)&vv;
          #pragma unroll
          for (int z=0;z<4;z++){
            unsigned lo = pw[z] & 0xffffu, hi = pw[z] >> 16;
            if (lo & 0x8000u) lo = 0;
            if (hi & 0x8000u) hi = 0;
            pw[z] = lo | (hi<<16);
          }
        } else if (ITRANS==2){
          unsigned* pw = (unsigned*)&vv;
          #pragma unroll
          for (int z=0;z<4;z++){
            unsigned lo = pw[z] & 0xffffu, hi = pw[z] >> 16;
            float f0 = __uint_as_float(lo<<16), f1 = __uint_as_float(hi<<16);
            float a0 = fabsf(f0)-thr, a1 = fabsf(f1)-thr;
            f0 = (a0>0.f)? copysignf(a0,f0) : 0.f;
            f1 = (a1>0.f)? copysignf(a1,f1) : 0.f;
            pw[z] = (unsigned)f2b(f0) | ((unsigned)f2b(f1)<<16);
          }
        }
        sm16[i] = vv;
      }
    }
  }
  __syncthreads();

  // ---- K loop (B-frag next-tap prefetch; per-(d,half) gating) ----
  f32x4 acc[MT][NH] = {};
  int presv = (NPASS==3) ? pres_p[set] : 0;
  for (int d = 1; d <= NPASS; ++d){
    int hm = (NPASS==3) ? ((presv >> ((d-1)*2)) & 3) : 3;
    if (NPASS==3 && hm==0) continue;
    const uint4* wbase = wp + (size_t)(d-1)*1152;
    bf16x8 bcur[NH];
    #pragma unroll
    for (int h=0; h<NH; ++h)
      if ((hm>>h)&1)
        bcur[h] = __builtin_bit_cast(bf16x8, wbase[(h*9 + 0)*64 + lane]);
    for (int t = 0; t < 9; ++t){
      bf16x8 bnxt[NH];
      if (t < 8){
        #pragma unroll
        for (int h=0; h<NH; ++h)
          if ((hm>>h)&1)
            bnxt[h] = __builtin_bit_cast(bf16x8, wbase[(h*9 + t+1)*64 + lane]);
      }
      int dy = (t/3 - 1)*d, dx = (t%3 - 1)*d;
      const uint4* sp = sm16 + q*TP + (H+dy)*TW + H + dx;
      #pragma unroll
      for (int mt=0; mt<MT; ++mt){
        int r = mt >> 1, xh = mt & 1;
        bf16x8 a = __builtin_bit_cast(bf16x8, sp[(w*RPW + r)*TW + xh*16 + m]);
        #pragma unroll
        for (int h=0; h<NH; ++h)
          if ((hm>>h)&1)
            acc[mt][h] = __builtin_amdgcn_mfma_f32_16x16x32_bf16(a, bcur[h], acc[mt][h], 0,0,0);
      }
      if (t < 8){
        #pragma unroll
        for (int h=0; h<NH; ++h)
          if ((hm>>h)&1) bcur[h] = bnxt[h];
      }
    }
  }

  // ---- epilogue ----
  if (EPI == 2){
    float ms = *ms_p;
    #pragma unroll
    for (int mt=0; mt<MT; ++mt){
      int r = mt >> 1, xh = mt & 1;
      int y = y0 + w*RPW + r;
      int x = x0 + xh*16 + q*4;
      #pragma unroll
      for (int h=0; h<NH; ++h){
        int oc = h*16 + m;
        if (oc < 3){
          size_t off = (((size_t)(b*3+oc)*HW + y)*HW + x);
          float4 e = ld4(epi_ptr + off);
          float4 o;
          o.x = e.x + ms*acc[mt][h][0];
          o.y = e.y + ms*acc[mt][h][1];
          o.z = e.z + ms*acc[mt][h][2];
          o.w = e.w + ms*acc[mt][h][3];
          *reinterpret_cast<float4*>((float*)outp + off) = o;
        }
      }
    }
  } else if (EPI == 3){
    // symloss: fp32 LDS transpose (stride 33)
    __syncthreads();
    float* swf = (float*)smem + (size_t)w*(PW*33);
    #pragma unroll
    for (int mt=0; mt<MT; ++mt){
      int r = mt >> 1, xh = mt & 1;
      #pragma unroll
      for (int h=0; h<NH; ++h){
        int oc = h*16 + m;
        #pragma unroll
        for (int reg=0; reg<4; ++reg){
          int P = r*32 + xh*16 + q*4 + reg;
          swf[P*33 + oc] = acc[mt][h][reg];
        }
      }
    }
    int row = lane >> 5, col = lane & 31;
    int y = y0 + w*RPW + row, x = x0 + col;
    const uint4* xb = (const uint4*)epi_ptr;
    float xd[32];
    #pragma unroll
    for (int g2=0; g2<4; ++g2){
      uint4 vv = xb[(((size_t)(b*4+g2)*HW + y)*HW + x)];
      const unsigned short* sp16 = (const unsigned short*)&vv;
      #pragma unroll
      for (int ci=0; ci<8; ++ci)
        xd[g2*8+ci] = __uint_as_float(((unsigned)sp16[ci])<<16);
    }
    float* out1f = (float*)outp;
    #pragma unroll
    for (int oc=0; oc<32; ++oc){
      float v = swf[lane*33 + oc] - xd[oc];
      out1f[(((size_t)(b*32+oc)*HW + y)*HW + x)] = v;
    }
  } else {
    // blocked bf16 out via per-wave LDS transpose, pixel stride 44 shorts
    __syncthreads();
    short* sw = (short*)smem + (size_t)w*PW*44;
    #pragma unroll
    for (int mt=0; mt<MT; ++mt){
      int r = mt >> 1, xh = mt & 1;
      #pragma unroll
      for (int h=0; h<NH; ++h){
        int oc = h*16 + m;
        #pragma unroll
        for (int reg=0; reg<4; ++reg){
          float v = acc[mt][h][reg];
          if (EPI==1) v = fmaxf(v, 0.f);
          int P = r*32 + xh*16 + q*4 + reg;
          sw[P*44 + oc] = (short)f2b(v);
        }
      }
    }
    const uint2* sw2 = (const uint2*)sw;
    #pragma unroll
    for (int i=0; i<PW/16; ++i){
      int id = i*64 + lane;
      int g2 = id / PW, P = id % PW;
      uint2 v0 = sw2[P*11 + g2*2];
      uint2 v1 = sw2[P*11 + g2*2 + 1];
      uint4 val = make_uint4(v0.x, v0.y, v1.x, v1.y);
      int y2 = y0 + w*RPW + (P>>5), x2 = x0 + (P&31);
      ((uint4*)outp)[(((size_t)(b*4+g2)*HW + y2)*HW + x2)] = val;
    }
  }
}

template<int EPI,int ROWS> struct epi_lds {
  static constexpr int SE = (EPI<=1) ? ROWS*8*44*2*4 : (EPI==3 ? ROWS*8*33*4*4 : 0);
};

template<int H,int NPASS,int NH,int ITRANS,int EPI,int ROWS>
__global__ __launch_bounds__(256, 2)
void mfma_conv_s(const uint4* __restrict__ inb, const uint4* __restrict__ wp,
                 void* __restrict__ outp,
                 const int* __restrict__ pres_p, int set,
                 const float* __restrict__ thr_p,
                 const float* __restrict__ epi_ptr,
                 const float* __restrict__ ms_p){
  constexpr int TP = (32+2*H)*(ROWS+2*H);
  constexpr int S1 = 4*TP*16;
  constexpr int S2 = epi_lds<EPI,ROWS>::SE;
  constexpr int SB = S1 > S2 ? S1 : S2;
  __shared__ __align__(16) char smem[SB];
  conv_body<H,NPASS,NH,ROWS,ITRANS,EPI>(smem, inb, wp, outp, pres_p, set,
                                        thr_p, epi_ptr, ms_p,
                                        blockIdx.x, blockIdx.y, blockIdx.z);
}

// dual-job variant: gridDim.z = NB*2, job = z>>2, b = z&3
template<int H,int NPASS,int NH,int ROWS,int IT0,int EP0,int IT1,int EP1>
__global__ __launch_bounds__(256, 2)
void mfma_conv_d(const uint4* __restrict__ in0, const uint4* __restrict__ in1,
                 const uint4* __restrict__ wp0, const uint4* __restrict__ wp1,
                 void* __restrict__ o0, void* __restrict__ o1,
                 const int* __restrict__ pres_p, int set,
                 const float* __restrict__ thr_p,
                 const float* __restrict__ e0, const float* __restrict__ e1,
                 const float* __restrict__ ms_p){
  constexpr int TP = (32+2*H)*(ROWS+2*H);
  constexpr int S1 = 4*TP*16;
  constexpr int SE0 = epi_lds<EP0,ROWS>::SE;
  constexpr int SE1 = epi_lds<EP1,ROWS>::SE;
  constexpr int S2 = SE0 > SE1 ? SE0 : SE1;
  constexpr int SB = S1 > S2 ? S1 : S2;
  __shared__ __align__(16) char smem[SB];
  int b = blockIdx.z & 3, job = blockIdx.z >> 2;
  if (job == 0)
    conv_body<H,NPASS,NH,ROWS,IT0,EP0>(smem, in0, wp0, o0, pres_p, set,
                                       thr_p, e0, ms_p, blockIdx.x, blockIdx.y, b);
  else
    conv_body<H,NPASS,NH,ROWS,IT1,EP1>(smem, in1, wp1, o1, pres_p, set,
                                       thr_p, e1, ms_p, blockIdx.x, blockIdx.y, b);
}

// ---------------------------------------------------------------------------
extern "C" void kernel_launch(void* const* d_in, const int* in_sizes, int n_in,
                              void* d_out, int out_size, void* d_ws, size_t ws_size,
                              hipStream_t stream) {
  const float* xprev = (const float*)d_in[0];
  const float* x     = (const float*)d_in[1];
  const float* PhiW  = (const float*)d_in[2];
  const float* PhiTW = (const float*)d_in[3];
  const float* PhiTb = (const float*)d_in[4];
  const float* lam   = (const float*)d_in[5];
  const float* sthr  = (const float*)d_in[6];
  const float* t_p   = (const float*)d_in[7];
  const float* mrg   = (const float*)d_in[8];
  const float* convD = (const float*)d_in[9];
  const float* conv3G= (const float*)d_in[10];
  const float* c1f_w=(const float*)d_in[11]; const float* c1f_p=(const float*)d_in[12];
  const float* c2f_w=(const float*)d_in[13]; const float* c2f_p=(const float*)d_in[14];
  const float* c1b_w=(const float*)d_in[15]; const float* c1b_p=(const float*)d_in[16];
  const float* c2b_w=(const float*)d_in[17]; const float* c2b_p=(const float*)d_in[18];
  const float* c1g_w=(const float*)d_in[19]; const float* c1g_p=(const float*)d_in[20];
  const float* c2g_w=(const float*)d_in[21]; const float* c2g_p=(const float*)d_in[22];

  char* ws = (char*)d_ws;
  const size_t BL = (size_t)NB*4*IMGSZ*16;          // blocked buffer 26,214,400 B
  uint4* xDb = (uint4*)(ws + 0*BL);
  uint4* Bb  = (uint4*)(ws + 1*BL);
  uint4* Cb  = (uint4*)(ws + 2*BL);
  uint4* Db  = (uint4*)(ws + 3*BL);
  uint4* Eb  = (uint4*)(ws + 4*BL);
  float* xDf = (float*)(ws + 5*BL);                 // region kept: PhiTB lives here
  float* x_input = (float*)(ws + 5*BL + 52428800);  // 4,915,200
  float* u       = (float*)(ws + 5*BL + 52428800 + 4915200);
  char*  phir    = ws + 5*BL + 52428800 + 2*4915200;
  uint4* PhiB    = (uint4*)phir;
  uint4* PhA     = (uint4*)(phir + 3145728);
  uint4* PhiTB   = (uint4*)xDf;
  uint4* Wp      = (uint4*)(ws + 5*BL + 52428800 + 3*4915200);   // 13*18432
  char*  mbase   = ws + 5*BL + 52428800 + 3*4915200 + 13*18432;
  int*   pres    = (int*)(mbase);

  float* out0 = (float*)d_out;
  float* out1 = out0 + (size_t)NB*3*IMGSZ;

  // wide-parallel head; meta folded into pack_w with parallel loads
  ew_u<<<1200, 256, 0, stream>>>(x, xprev, t_p, u, 307200);
  pack_phib<<<384, 256, 0, stream>>>(PhiW, PhiB);
  pack_phitb<<<384, 256, 0, stream>>>(PhiTW, PhiTB);
  pack_w<<<13, 256, 0, stream>>>(c1f_w,c2f_w,c1b_w,c2b_w,c1g_w,c2g_w,conv3G,
                                 c1f_p,c2f_p,c1b_p,c2b_p,c1g_p,c2g_p,
                                 pres, Wp);

  // zeta path
  phi_gemm<<<dim3(25,4,3), 256, 0, stream>>>(u, PhiB, PhA);
  phit_gemm<<<dim3(25,4,3), 256, 0, stream>>>(PhA, PhiTB, u, PhiTb, lam, x_input);

  // x_D = conv_D(x_input): fused direct -> blocked bf16
  conv_direct_blocked<<<dim3(400,4,NB), 256, 0, stream>>>(x_input, convD, xDb);

  dim3 mg(10,40,NB);        // 8-row tiles
  dim3 mg2(10,40,NB*2);     // dual-job
  uint4* W_c1f = Wp + 0*1152;
  uint4* W_c2f = Wp + 1*1152;   // 3 classes
  uint4* W_c1b = Wp + 4*1152;
  uint4* W_c2b = Wp + 5*1152;   // 3 classes
  uint4* W_c1g = Wp + 8*1152;
  uint4* W_c2g = Wp + 9*1152;   // 3 classes
  uint4* W_g3  = Wp + 12*1152;

  // h1 = relu(adconv(x_D, c1f))
  mfma_conv_s<1,1,2,0,1,8><<<mg,256,0,stream>>>(xDb, W_c1f, Bb, nullptr,0, nullptr,nullptr,nullptr);
  // x_forward = adconv(h1, c2f)
  mfma_conv_s<3,3,2,0,0,8><<<mg,256,0,stream>>>(Bb, W_c2f, Cb, pres,1, nullptr,nullptr,nullptr);
  // h2 = relu(adconv(soft(x_forward), c1f)) -> Db ; h5 = relu(adconv(x_forward, c1b)) -> Bb
  mfma_conv_d<1,1,2,8, 2,1, 0,1><<<mg2,256,0,stream>>>(Cb, Cb, W_c1f, W_c1b, Db, Bb,
                                                       nullptr,0, sthr, nullptr,nullptr, nullptr);
  // relu(x_backward) -> Eb ; symloss = adconv(h5, c2b) - x_D -> out1
  mfma_conv_d<3,3,2,8, 0,1, 0,3><<<mg2,256,0,stream>>>(Db, Bb, W_c2b, W_c2b, Eb, out1,
                                                       pres,3, nullptr, nullptr, (const float*)xDb, nullptr);
  // relu(h3) = relu(adconv(relu_xb, c1g)) -> Db
  mfma_conv_s<1,1,2,0,1,8><<<mg,256,0,stream>>>(Eb, W_c1g, Db, nullptr,0, nullptr,nullptr,nullptr);
  // h4 = adconv(relu_h3, c2g)
  mfma_conv_s<3,3,2,0,0,8><<<mg,256,0,stream>>>(Db, W_c2g, Eb, pres,5, nullptr,nullptr,nullptr);
  // x_pred = x_input + ms * conv3_G(h4)  -> out0
  mfma_conv_s<1,1,1,0,2,8><<<mg,256,0,stream>>>(Eb, W_g3, out0, nullptr,0, nullptr, x_input, mrg);
}

// Round 11
// 365.828 us; speedup vs baseline: 1.0874x; 1.0874x over previous
//
#include <hip/hip_runtime.h>
#include <math.h>

#define HW 320
#define IMGSZ (HW*HW)
#define NB 4

typedef __bf16 bf16x8 __attribute__((ext_vector_type(8)));
typedef float  f32x4  __attribute__((ext_vector_type(4)));

__device__ __forceinline__ float4 ld4(const float* p){ return *reinterpret_cast<const float4*>(p); }

__device__ __forceinline__ unsigned short f2b(float f){
  unsigned u = __float_as_uint(f);
  unsigned r = (u + 0x7fffu + ((u>>16)&1u)) >> 16;
  return (unsigned short)r;
}

// u = x + xi*(x - xprev)
__global__ void ew_u(const float* __restrict__ x, const float* __restrict__ xprev,
                     const float* __restrict__ t_p, float* __restrict__ u, int n4){
  int i = blockIdx.x*blockDim.x + threadIdx.x;
  if (i >= n4) return;
  float t = *t_p;
  float tplus = (1.f + sqrtf(1.f + 4.f*t*t)) * 0.5f;
  float xi = (t - 1.f)/tplus;
  float4 xv = ld4(x + 4*i); float4 pv = ld4(xprev + 4*i);
  float4 r;
  r.x = xv.x + xi*(xv.x-pv.x);
  r.y = xv.y + xi*(xv.y-pv.y);
  r.z = xv.z + xi*(xv.z-pv.z);
  r.w = xv.w + xi*(xv.w-pv.w);
  *reinterpret_cast<float4*>(u + 4*i) = r;
}

// ---------------------------------------------------------------------------
// Phi path as split-bf16 MFMA GEMMs (hi/lo fp32 emulation, AhBh+AhBl+AlBh).
// ---------------------------------------------------------------------------

// PhiW(256,3,32,32) -> PhiB[c][mt4][ks32][nf4][hilo2][lane64] uint4
__global__ void pack_phib(const float* __restrict__ PhiW, uint4* __restrict__ PhiB){
  int idx = blockIdx.x*256 + threadIdx.x;   // 98304 total
  int lane = idx & 63;
  int t2 = idx >> 6;                        // ((c*4+mt)*32+ks)*4+nf
  int nf = t2 & 3, ks = (t2>>2)&31, cm = t2>>7;
  int m = (cm&3)*64 + nf*16 + (lane&15);
  int c = cm>>2;
  int kbase = ks*32 + (lane>>4)*8;
  const float* src = PhiW + ((size_t)m*3 + c)*1024 + kbase;
  float4 v0 = ld4(src), v1 = ld4(src+4);
  float vals[8] = {v0.x,v0.y,v0.z,v0.w,v1.x,v1.y,v1.z,v1.w};
  uint4 hi, lo; unsigned* hw = (unsigned*)&hi; unsigned* lw = (unsigned*)&lo;
  #pragma unroll
  for (int p=0;p<4;p++){
    unsigned h0 = f2b(vals[2*p]), h1 = f2b(vals[2*p+1]);
    float r0 = vals[2*p]   - __uint_as_float(h0<<16);
    float r1 = vals[2*p+1] - __uint_as_float(h1<<16);
    hw[p] = h0 | (h1<<16);
    lw[p] = (unsigned)f2b(r0) | ((unsigned)f2b(r1)<<16);
  }
  PhiB[(size_t)t2*128 + lane] = hi;
  PhiB[(size_t)t2*128 + 64 + lane] = lo;
}

// PhiTW(3*1024,256,1,1) -> PhiTB[c][n64x16][ks8][nf4][hilo2][lane64] uint4
__global__ void pack_phitb(const float* __restrict__ PhiTW, uint4* __restrict__ PhiTB){
  int idx = blockIdx.x*256 + threadIdx.x;   // 98304 total
  int lane = idx & 63;
  int t2 = idx >> 6;                        // ((c*16+n64)*8+ks)*4+nf
  int nf = t2 & 3, ks = (t2>>2)&7, cn = t2>>5;
  int n = (cn&15)*64 + nf*16 + (lane&15);
  int c = cn>>4;
  int kbase = ks*32 + (lane>>4)*8;
  const float* src = PhiTW + ((size_t)c*1024 + n)*256 + kbase;
  float4 v0 = ld4(src), v1 = ld4(src+4);
  float vals[8] = {v0.x,v0.y,v0.z,v0.w,v1.x,v1.y,v1.z,v1.w};
  uint4 hi, lo; unsigned* hw = (unsigned*)&hi; unsigned* lw = (unsigned*)&lo;
  #pragma unroll
  for (int p=0;p<4;p++){
    unsigned h0 = f2b(vals[2*p]), h1 = f2b(vals[2*p+1]);
    float r0 = vals[2*p]   - __uint_as_float(h0<<16);
    float r1 = vals[2*p+1] - __uint_as_float(h1<<16);
    hw[p] = h0 | (h1<<16);
    lw[p] = (unsigned)f2b(r0) | ((unsigned)f2b(r1)<<16);
  }
  PhiTB[(size_t)t2*128 + lane] = hi;
  PhiTB[(size_t)t2*128 + 64 + lane] = lo;
}

// grid(25 rowtiles, 4 mtiles, 3 c) x 256.  Waves K-split (256 k each), LDS reduce.
__global__ __launch_bounds__(256)
void phi_gemm(const float* __restrict__ u, const uint4* __restrict__ PhiB,
              uint4* __restrict__ PhA){
  __shared__ uint4 As[2][2048];   // [hilo][kb*16+m], 64 KB
  const int rt = blockIdx.x, mt = blockIdx.y, c = blockIdx.z;
  const int tid = threadIdx.x, lane = tid & 63, w = tid >> 6;

  for (int idx = tid; idx < 4096; idx += 256){
    int m = idx >> 8;
    int f4 = idx & 255;
    int k = f4*4;
    int r = rt*16 + m;
    int b = r/100, blk = r - b*100;
    int bh = blk/10, bw = blk - bh*10;
    int ip = k >> 5, jp = k & 31;
    float4 v = ld4(u + ((size_t)((b*3+c)*HW + bh*32+ip))*HW + bw*32 + jp);
    float vv[4] = {v.x,v.y,v.z,v.w};
    unsigned hh[4], ll[4];
    #pragma unroll
    for (int e=0;e<4;e++){
      hh[e] = f2b(vv[e]);
      ll[e] = f2b(vv[e] - __uint_as_float(hh[e]<<16));
    }
    int kb = k >> 3, off = (k & 7) ? 1 : 0;
    ((uint2*)&As[0][kb*16+m])[off] = make_uint2(hh[0]|(hh[1]<<16), hh[2]|(hh[3]<<16));
    ((uint2*)&As[1][kb*16+m])[off] = make_uint2(ll[0]|(ll[1]<<16), ll[2]|(ll[3]<<16));
  }
  __syncthreads();

  f32x4 acc[4] = {};
  const uint4* bbase = PhiB + (size_t)(c*4+mt)*32*512;
  for (int ksl = 0; ksl < 8; ++ksl){
    int ks = w*8 + ksl;
    bf16x8 ah = __builtin_bit_cast(bf16x8, As[0][ks*64 + lane]);
    bf16x8 al = __builtin_bit_cast(bf16x8, As[1][ks*64 + lane]);
    #pragma unroll
    for (int nf=0; nf<4; ++nf){
      const uint4* bp = bbase + ((size_t)ks*4 + nf)*128;
      bf16x8 bh = __builtin_bit_cast(bf16x8, bp[lane]);
      bf16x8 bl = __builtin_bit_cast(bf16x8, bp[64 + lane]);
      acc[nf] = __builtin_amdgcn_mfma_f32_16x16x32_bf16(ah, bh, acc[nf], 0,0,0);
      acc[nf] = __builtin_amdgcn_mfma_f32_16x16x32_bf16(ah, bl, acc[nf], 0,0,0);
      acc[nf] = __builtin_amdgcn_mfma_f32_16x16x32_bf16(al, bh, acc[nf], 0,0,0);
    }
  }

  __syncthreads();
  float* rf = (float*)As;
  #pragma unroll
  for (int nf=0; nf<4; ++nf)
    ((float4*)rf)[(w*64+lane)*4 + nf] = *(float4*)&acc[nf];
  __syncthreads();

  int o = tid*4;
  int i = o >> 6, j = o & 63;
  int nf = j >> 4, q = i >> 2, reg = i & 3;
  unsigned hh[4], ll[4];
  #pragma unroll
  for (int e=0;e<4;e++){
    int ls = q*16 + (j&15) + e;
    float v = rf[(0*64+ls)*16 + nf*4+reg] + rf[(1*64+ls)*16 + nf*4+reg]
            + rf[(2*64+ls)*16 + nf*4+reg] + rf[(3*64+ls)*16 + nf*4+reg];
    hh[e] = f2b(v);
    ll[e] = f2b(v - __uint_as_float(hh[e]<<16));
  }
  int kb = mt*8 + (j>>3);
  int off = (j & 7) ? 1 : 0;
  ((uint2*)&PhA[((size_t)(0*3+c)*25 + rt)*512 + kb*16 + i])[off] =
      make_uint2(hh[0]|(hh[1]<<16), hh[2]|(hh[3]<<16));
  ((uint2*)&PhA[((size_t)(1*3+c)*25 + rt)*512 + kb*16 + i])[off] =
      make_uint2(ll[0]|(ll[1]<<16), ll[2]|(ll[3]<<16));
}

// grid(25 rowtiles, 4 ntiles-of-256, 3 c) x 256.  Waves split N (64 each).
__global__ __launch_bounds__(256)
void phit_gemm(const uint4* __restrict__ PhA, const uint4* __restrict__ PhiTB,
               const float* __restrict__ u, const float* __restrict__ PhiTb,
               const float* __restrict__ lam_p, float* __restrict__ x_input){
  const int rt = blockIdx.x, nt4 = blockIdx.y, c = blockIdx.z;
  const int tid = threadIdx.x, lane = tid & 63, w = tid >> 6;
  f32x4 acc[4] = {};
  const uint4* ah_base = PhA + ((size_t)(0*3+c)*25 + rt)*512;
  const uint4* al_base = PhA + ((size_t)(1*3+c)*25 + rt)*512;
  const uint4* bbase = PhiTB + (size_t)(c*16 + nt4*4 + w)*8*512;
  #pragma unroll
  for (int ks=0; ks<8; ++ks){
    bf16x8 ah = __builtin_bit_cast(bf16x8, ah_base[ks*64 + lane]);
    bf16x8 al = __builtin_bit_cast(bf16x8, al_base[ks*64 + lane]);
    #pragma unroll
    for (int nf=0; nf<4; ++nf){
      const uint4* bp = bbase + ((size_t)ks*4 + nf)*128;
      bf16x8 bh = __builtin_bit_cast(bf16x8, bp[lane]);
      bf16x8 bl = __builtin_bit_cast(bf16x8, bp[64 + lane]);
      acc[nf] = __builtin_amdgcn_mfma_f32_16x16x32_bf16(ah, bh, acc[nf], 0,0,0);
      acc[nf] = __builtin_amdgcn_mfma_f32_16x16x32_bf16(ah, bl, acc[nf], 0,0,0);
      acc[nf] = __builtin_amdgcn_mfma_f32_16x16x32_bf16(al, bh, acc[nf], 0,0,0);
    }
  }
  float lam = *lam_p;
  int q = lane >> 4, jl = lane & 15;
  #pragma unroll
  for (int nf=0; nf<4; ++nf){
    int n = nt4*256 + w*64 + nf*16 + jl;
    int ip = n >> 5, jp = n & 31;
    #pragma unroll
    for (int reg=0; reg<4; ++reg){
      int r = rt*16 + q*4 + reg;
      int b = r/100, blk = r - b*100;
      int bh_ = blk/10, bw_ = blk - bh_*10;
      size_t g = ((size_t)((b*3+c)*HW + bh_*32+ip))*HW + bw_*32 + jp;
      x_input[g] = u[g] - lam*acc[nf][reg] + lam*PhiTb[g];
    }
  }
}

// ---------------------------------------------------------------------------
// convD fused: 3x3 conv (3ch -> 32oc) from fp32 NCHW directly to blocked bf16.
// ---------------------------------------------------------------------------
__global__ __launch_bounds__(256)
void conv_direct_blocked(const float* __restrict__ in, const float* __restrict__ wts,
                         uint4* __restrict__ dst){
  const int tile = blockIdx.x, g = blockIdx.y, b = blockIdx.z;
  const int x0 = (tile % 20)*16, y0 = (tile / 20)*16;
  const int tid = threadIdx.x;
  __shared__ float ism[3*18*20];
  __shared__ float wsm[8*27];
  for (int i = tid; i < 3*18*18; i += 256){
    int ic = i / 324; int rr = i - ic*324; int r = rr/18, c = rr - r*18;
    int gy = y0 - 1 + r, gx = x0 - 1 + c;
    float v = 0.f;
    if (gy>=0 && gy<HW && gx>=0 && gx<HW)
      v = in[(size_t)(b*3+ic)*IMGSZ + (size_t)gy*HW + gx];
    ism[(ic*18+r)*20 + c] = v;
  }
  if (tid < 216) wsm[tid] = wts[(size_t)(g*8 + tid/27)*27 + (tid%27)];
  __syncthreads();

  const int px = tid & 15, py = tid >> 4;
  float acc[8] = {};
  #pragma unroll
  for (int ic=0; ic<3; ++ic)
    #pragma unroll
    for (int ky=0; ky<3; ++ky)
      #pragma unroll
      for (int kx=0; kx<3; ++kx){
        float v = ism[(ic*18+py+ky)*20 + px+kx];
        #pragma unroll
        for (int o=0;o<8;o++)
          acc[o] += wsm[o*27 + ic*9 + ky*3 + kx] * v;
      }
  uint4 ov; unsigned* ow = (unsigned*)&ov;
  #pragma unroll
  for (int p=0;p<4;p++)
    ow[p] = (unsigned)f2b(acc[2*p]) | ((unsigned)f2b(acc[2*p+1])<<16);
  dst[(((size_t)(b*4+g)*HW + (y0+py))*HW + x0+px)] = ov;
}

// ---------------------------------------------------------------------------
// Weight packing with meta folded in — parallel meta loads.
// pres[set]: bit (d-1)*2 + h set iff dilation class d has >=1 output channel
// in oc-half h (classes oc-contiguous after the counting sort).
// ---------------------------------------------------------------------------
__global__ void pack_w(const float* w0,const float* w1,const float* w2,
                       const float* w3,const float* w4,const float* w5,
                       const float* w6,
                       const float* p0,const float* p1,const float* p2,
                       const float* p3,const float* p4,const float* p5,
                       int* __restrict__ pres, uint4* __restrict__ wp){
  const float* wsel[7] = {w0,w1,w2,w3,w4,w5,w6};
  const float* psel[6] = {p0,p1,p2,p3,p4,p5};
  const int set_of[13]  = {0,1,1,1,2,3,3,3,4,5,5,5,6};
  const int cls_of[13]  = {1,1,2,3,1,1,2,3,1,1,2,3,1};
  const int Ts[6] = {1,3,1,3,1,3};
  int slot = blockIdx.x;
  int set = set_of[slot], cls = cls_of[slot];

  __shared__ int   s_idx[32];
  __shared__ float s_mx[32];
  __shared__ int   s_src[32];
  __shared__ int   s_d[32];
  __shared__ float s_scale[32];

  if (set < 6 && threadIdx.x < 32){
    const float* para = psel[set];
    int T = Ts[set];
    int c = threadIdx.x;
    int best = 0; float bv = para[c*T];
    for (int t=1;t<T;t++){ float v = para[c*T+t]; if (v>bv){bv=v;best=t;} }
    s_idx[c] = best; s_mx[c] = bv;
  }
  __syncthreads();

  if (set < 6 && threadIdx.x == 0){
    float sum[3]={0.f,0.f,0.f}; int cnt[3]={0,0,0};
    for (int c=0;c<32;c++){ sum[s_idx[c]] += s_mx[c]; cnt[s_idx[c]]++; }
    float mul[3];
    for (int t=0;t<3;t++) mul[t] = sum[t]/fmaxf((float)cnt[t],1.f)+1.f;
    int off[3]; off[0]=0; off[1]=cnt[0]; off[2]=cnt[0]+cnt[1];
    int perm[32];
    for (int c=0;c<32;c++) perm[off[s_idx[c]]++] = c;   // stable counting sort
    int pb = 0;
    for (int k=0;k<32;k++){
      int s = perm[k];
      s_src[k]=s; s_d[k]=s_idx[s]+1; s_scale[k]=mul[s_idx[s]];
      pb |= 1 << ((s_idx[s])*2 + (k>>4));   // (d-1)*2 + half
    }
    if (cls == 1) pres[set] = pb;
  }
  __syncthreads();

  const float* W = wsel[set];
  unsigned short* out = (unsigned short*)(wp + (size_t)slot*1152);
  for (int v = threadIdx.x; v < 9216; v += 256){
    int j = v & 7;
    int lane = (v >> 3) & 63;
    int rest = v >> 9;           // h*9+t
    int t = rest % 9, h = rest / 9;
    int ocl = lane & 15, q = lane >> 4;
    int oc = h*16 + ocl;
    int ic = q*8 + j;
    float val = 0.f;
    if (set == 6){
      if (oc < 3) val = W[(size_t)oc*(32*9) + ic*9 + t];
    } else {
      if (s_d[oc] == cls){
        int src = s_src[oc];
        val = W[(size_t)src*(32*9) + ic*9 + t] * s_scale[oc];
      }
    }
    out[v] = f2b(val);
  }
}

// ---------------------------------------------------------------------------
// K-pass for one dilation class, half-mask HM known at COMPILE TIME:
// each instantiation is branch-free (HM=3 == R8's proven body).
// ---------------------------------------------------------------------------
template<int H,int NH,int ROWS,int HM>
__device__ __forceinline__ void kpass(const uint4* __restrict__ sm16,
    const uint4* __restrict__ wbase, f32x4 (&acc)[ROWS/2][NH],
    int d, int w, int q, int m, int lane){
  constexpr int TW = 32 + 2*H, TP = TW*(ROWS + 2*H);
  constexpr int MT = ROWS/2, RPW = ROWS/4;
  bf16x8 b0, b1;
  if constexpr (HM & 1)
    b0 = __builtin_bit_cast(bf16x8, wbase[(0*9 + 0)*64 + lane]);
  if constexpr ((NH > 1) && (HM & 2))
    b1 = __builtin_bit_cast(bf16x8, wbase[(1*9 + 0)*64 + lane]);
  for (int t = 0; t < 9; ++t){
    bf16x8 n0, n1;
    if (t < 8){
      if constexpr (HM & 1)
        n0 = __builtin_bit_cast(bf16x8, wbase[(0*9 + t+1)*64 + lane]);
      if constexpr ((NH > 1) && (HM & 2))
        n1 = __builtin_bit_cast(bf16x8, wbase[(1*9 + t+1)*64 + lane]);
    }
    int dy = (t/3 - 1)*d, dx = (t%3 - 1)*d;
    const uint4* sp = sm16 + q*TP + (H+dy)*TW + H + dx;
    #pragma unroll
    for (int mt=0; mt<MT; ++mt){
      int r = mt >> 1, xh = mt & 1;
      bf16x8 a = __builtin_bit_cast(bf16x8, sp[(w*RPW + r)*TW + xh*16 + m]);
      if constexpr (HM & 1)
        acc[mt][0] = __builtin_amdgcn_mfma_f32_16x16x32_bf16(a, b0, acc[mt][0], 0,0,0);
      if constexpr ((NH > 1) && (HM & 2))
        acc[mt][1] = __builtin_amdgcn_mfma_f32_16x16x32_bf16(a, b1, acc[mt][1], 0,0,0);
    }
    if (t < 8){
      if constexpr (HM & 1) b0 = n0;
      if constexpr ((NH > 1) && (HM & 2)) b1 = n1;
    }
  }
}

// ---------------------------------------------------------------------------
// MFMA conv body. Block 256thr=4 waves; block tile 32 x ROWS; wave: ROWS/4 rows.
// ROWS=8, full-batch reg staging, B-frag next-tap prefetch.
// NPASS==3: per-(d,half) gating via compile-time kpass variants, selected by a
// wave-uniform scalar branch OUTSIDE the inner loops.
// EPI: 0 none / 1 relu (blocked bf16 out via LDS transpose)
//      2 merge: out0 fp32 = epi + ms*acc (oc<3)
//      3 sub:   out1 fp32 = acc - bf16(epi blocked), via fp32 LDS transpose
// ---------------------------------------------------------------------------
template<int H,int NPASS,int NH,int ROWS,int ITRANS,int EPI>
__device__ __forceinline__ void conv_body(char* smem,
    const uint4* __restrict__ inb, const uint4* __restrict__ wp,
    void* __restrict__ outp, const int* __restrict__ pres_p, int set,
    const float* __restrict__ thr_p, const float* __restrict__ epi_ptr,
    const float* __restrict__ ms_p, int tx, int ty, int b){
  constexpr int TW = 32 + 2*H, TH = ROWS + 2*H, TP = TW*TH;
  constexpr int RPW = ROWS/4;          // rows per wave
  constexpr int MT  = ROWS/2;          // mfma tiles per wave
  constexpr int PW  = ROWS*8;          // pixels per wave

  const int x0 = tx*32, y0 = ty*ROWS;
  const int tid = threadIdx.x;
  const int lane = tid & 63, w = tid >> 6;
  const int m = lane & 15, q = lane >> 4;

  // ---- stage input tile: full-batch loads, then transform + LDS write ----
  float thr = (ITRANS==2) ? *thr_p : 0.f;
  uint4* sm16 = (uint4*)smem;
  constexpr int TOT = 4*TP;
  constexpr int NSTG = (TOT + 255)/256;
  {
    uint4 v[NSTG];
    #pragma unroll
    for (int uu=0; uu<NSTG; ++uu){
      v[uu] = make_uint4(0,0,0,0);
      int i = tid + uu*256;
      if (i < TOT){
        int g = i / TP; int rr = i - g*TP; int r = rr / TW; int c = rr - r*TW;
        int gy = y0 - H + r, gx = x0 - H + c;
        if (gy>=0 && gy<HW && gx>=0 && gx<HW)
          v[uu] = inb[(((size_t)(b*4+g)*HW + gy)*HW + gx)];
      }
    }
    #pragma unroll
    for (int uu=0; uu<NSTG; ++uu){
      int i = tid + uu*256;
      if (i < TOT){
        uint4 vv = v[uu];
        if (ITRANS==1){
          unsigned* pw = (unsigned*)&vv;
          #pragma unroll
          for (int z=0;z<4;z++){
            unsigned lo = pw[z] & 0xffffu, hi = pw[z] >> 16;
            if (lo & 0x8000u) lo = 0;
            if (hi & 0x8000u) hi = 0;
            pw[z] = lo | (hi<<16);
          }
        } else if (ITRANS==2){
          unsigned* pw = (unsigned*)&vv;
          #pragma unroll
          for (int z=0;z<4;z++){
            unsigned lo = pw[z] & 0xffffu, hi = pw[z] >> 16;
            float f0 = __uint_as_float(lo<<16), f1 = __uint_as_float(hi<<16);
            float a0 = fabsf(f0)-thr, a1 = fabsf(f1)-thr;
            f0 = (a0>0.f)? copysignf(a0,f0) : 0.f;
            f1 = (a1>0.f)? copysignf(a1,f1) : 0.f;
            pw[z] = (unsigned)f2b(f0) | ((unsigned)f2b(f1)<<16);
          }
        }
        sm16[i] = vv;
      }
    }
  }
  __syncthreads();

  // ---- K loop ----
  f32x4 acc[MT][NH] = {};
  if constexpr (NPASS == 3){
    int presv = pres_p[set];
    for (int d = 1; d <= 3; ++d){
      int hm = (presv >> ((d-1)*2)) & 3;
      if (hm == 0) continue;
      const uint4* wbase = wp + (size_t)(d-1)*1152;
      if (hm == 3)      kpass<H,NH,ROWS,3>(sm16, wbase, acc, d, w, q, m, lane);
      else if (hm == 1) kpass<H,NH,ROWS,1>(sm16, wbase, acc, d, w, q, m, lane);
      else              kpass<H,NH,ROWS,2>(sm16, wbase, acc, d, w, q, m, lane);
    }
  } else {
    kpass<H,NH,ROWS,3>(sm16, wp, acc, 1, w, q, m, lane);
  }

  // ---- epilogue ----
  if (EPI == 2){
    float ms = *ms_p;
    #pragma unroll
    for (int mt=0; mt<MT; ++mt){
      int r = mt >> 1, xh = mt & 1;
      int y = y0 + w*RPW + r;
      int x = x0 + xh*16 + q*4;
      #pragma unroll
      for (int h=0; h<NH; ++h){
        int oc = h*16 + m;
        if (oc < 3){
          size_t off = (((size_t)(b*3+oc)*HW + y)*HW + x);
          float4 e = ld4(epi_ptr + off);
          float4 o;
          o.x = e.x + ms*acc[mt][h][0];
          o.y = e.y + ms*acc[mt][h][1];
          o.z = e.z + ms*acc[mt][h][2];
          o.w = e.w + ms*acc[mt][h][3];
          *reinterpret_cast<float4*>((float*)outp + off) = o;
        }
      }
    }
  } else if (EPI == 3){
    // symloss: fp32 LDS transpose (stride 33)
    __syncthreads();
    float* swf = (float*)smem + (size_t)w*(PW*33);
    #pragma unroll
    for (int mt=0; mt<MT; ++mt){
      int r = mt >> 1, xh = mt & 1;
      #pragma unroll
      for (int h=0; h<NH; ++h){
        int oc = h*16 + m;
        #pragma unroll
        for (int reg=0; reg<4; ++reg){
          int P = r*32 + xh*16 + q*4 + reg;
          swf[P*33 + oc] = acc[mt][h][reg];
        }
      }
    }
    int row = lane >> 5, col = lane & 31;
    int y = y0 + w*RPW + row, x = x0 + col;
    const uint4* xb = (const uint4*)epi_ptr;
    float xd[32];
    #pragma unroll
    for (int g2=0; g2<4; ++g2){
      uint4 vv = xb[(((size_t)(b*4+g2)*HW + y)*HW + x)];
      const unsigned short* sp16 = (const unsigned short*)&vv;
      #pragma unroll
      for (int ci=0; ci<8; ++ci)
        xd[g2*8+ci] = __uint_as_float(((unsigned)sp16[ci])<<16);
    }
    float* out1f = (float*)outp;
    #pragma unroll
    for (int oc=0; oc<32; ++oc){
      float v = swf[lane*33 + oc] - xd[oc];
      out1f[(((size_t)(b*32+oc)*HW + y)*HW + x)] = v;
    }
  } else {
    // blocked bf16 out via per-wave LDS transpose, pixel stride 44 shorts
    __syncthreads();
    short* sw = (short*)smem + (size_t)w*PW*44;
    #pragma unroll
    for (int mt=0; mt<MT; ++mt){
      int r = mt >> 1, xh = mt & 1;
      #pragma unroll
      for (int h=0; h<NH; ++h){
        int oc = h*16 + m;
        #pragma unroll
        for (int reg=0; reg<4; ++reg){
          float v = acc[mt][h][reg];
          if (EPI==1) v = fmaxf(v, 0.f);
          int P = r*32 + xh*16 + q*4 + reg;
          sw[P*44 + oc] = (short)f2b(v);
        }
      }
    }
    const uint2* sw2 = (const uint2*)sw;
    #pragma unroll
    for (int i=0; i<PW/16; ++i){
      int id = i*64 + lane;
      int g2 = id / PW, P = id % PW;
      uint2 v0 = sw2[P*11 + g2*2];
      uint2 v1 = sw2[P*11 + g2*2 + 1];
      uint4 val = make_uint4(v0.x, v0.y, v1.x, v1.y);
      int y2 = y0 + w*RPW + (P>>5), x2 = x0 + (P&31);
      ((uint4*)outp)[(((size_t)(b*4+g2)*HW + y2)*HW + x2)] = val;
    }
  }
}

template<int EPI,int ROWS> struct epi_lds {
  static constexpr int SE = (EPI<=1) ? ROWS*8*44*2*4 : (EPI==3 ? ROWS*8*33*4*4 : 0);
};

template<int H,int NPASS,int NH,int ITRANS,int EPI,int ROWS>
__global__ __launch_bounds__(256, 2)
void mfma_conv_s(const uint4* __restrict__ inb, const uint4* __restrict__ wp,
                 void* __restrict__ outp,
                 const int* __restrict__ pres_p, int set,
                 const float* __restrict__ thr_p,
                 const float* __restrict__ epi_ptr,
                 const float* __restrict__ ms_p){
  constexpr int TP = (32+2*H)*(ROWS+2*H);
  constexpr int S1 = 4*TP*16;
  constexpr int S2 = epi_lds<EPI,ROWS>::SE;
  constexpr int SB = S1 > S2 ? S1 : S2;
  __shared__ __align__(16) char smem[SB];
  conv_body<H,NPASS,NH,ROWS,ITRANS,EPI>(smem, inb, wp, outp, pres_p, set,
                                        thr_p, epi_ptr, ms_p,
                                        blockIdx.x, blockIdx.y, blockIdx.z);
}

// dual-job variant: gridDim.z = NB*2, job = z>>2, b = z&3
template<int H,int NPASS,int NH,int ROWS,int IT0,int EP0,int IT1,int EP1>
__global__ __launch_bounds__(256, 2)
void mfma_conv_d(const uint4* __restrict__ in0, const uint4* __restrict__ in1,
                 const uint4* __restrict__ wp0, const uint4* __restrict__ wp1,
                 void* __restrict__ o0, void* __restrict__ o1,
                 const int* __restrict__ pres_p, int set,
                 const float* __restrict__ thr_p,
                 const float* __restrict__ e0, const float* __restrict__ e1,
                 const float* __restrict__ ms_p){
  constexpr int TP = (32+2*H)*(ROWS+2*H);
  constexpr int S1 = 4*TP*16;
  constexpr int SE0 = epi_lds<EP0,ROWS>::SE;
  constexpr int SE1 = epi_lds<EP1,ROWS>::SE;
  constexpr int S2 = SE0 > SE1 ? SE0 : SE1;
  constexpr int SB = S1 > S2 ? S1 : S2;
  __shared__ __align__(16) char smem[SB];
  int b = blockIdx.z & 3, job = blockIdx.z >> 2;
  if (job == 0)
    conv_body<H,NPASS,NH,ROWS,IT0,EP0>(smem, in0, wp0, o0, pres_p, set,
                                       thr_p, e0, ms_p, blockIdx.x, blockIdx.y, b);
  else
    conv_body<H,NPASS,NH,ROWS,IT1,EP1>(smem, in1, wp1, o1, pres_p, set,
                                       thr_p, e1, ms_p, blockIdx.x, blockIdx.y, b);
}

// ---------------------------------------------------------------------------
extern "C" void kernel_launch(void* const* d_in, const int* in_sizes, int n_in,
                              void* d_out, int out_size, void* d_ws, size_t ws_size,
                              hipStream_t stream) {
  const float* xprev = (const float*)d_in[0];
  const float* x     = (const float*)d_in[1];
  const float* PhiW  = (const float*)d_in[2];
  const float* PhiTW = (const float*)d_in[3];
  const float* PhiTb = (const float*)d_in[4];
  const float* lam   = (const float*)d_in[5];
  const float* sthr  = (const float*)d_in[6];
  const float* t_p   = (const float*)d_in[7];
  const float* mrg   = (const float*)d_in[8];
  const float* convD = (const float*)d_in[9];
  const float* conv3G= (const float*)d_in[10];
  const float* c1f_w=(const float*)d_in[11]; const float* c1f_p=(const float*)d_in[12];
  const float* c2f_w=(const float*)d_in[13]; const float* c2f_p=(const float*)d_in[14];
  const float* c1b_w=(const float*)d_in[15]; const float* c1b_p=(const float*)d_in[16];
  const float* c2b_w=(const float*)d_in[17]; const float* c2b_p=(const float*)d_in[18];
  const float* c1g_w=(const float*)d_in[19]; const float* c1g_p=(const float*)d_in[20];
  const float* c2g_w=(const float*)d_in[21]; const float* c2g_p=(const float*)d_in[22];

  char* ws = (char*)d_ws;
  const size_t BL = (size_t)NB*4*IMGSZ*16;          // blocked buffer 26,214,400 B
  uint4* xDb = (uint4*)(ws + 0*BL);
  uint4* Bb  = (uint4*)(ws + 1*BL);
  uint4* Cb  = (uint4*)(ws + 2*BL);
  uint4* Db  = (uint4*)(ws + 3*BL);
  uint4* Eb  = (uint4*)(ws + 4*BL);
  float* xDf = (float*)(ws + 5*BL);                 // region kept: PhiTB lives here
  float* x_input = (float*)(ws + 5*BL + 52428800);  // 4,915,200
  float* u       = (float*)(ws + 5*BL + 52428800 + 4915200);
  char*  phir    = ws + 5*BL + 52428800 + 2*4915200;
  uint4* PhiB    = (uint4*)phir;
  uint4* PhA     = (uint4*)(phir + 3145728);
  uint4* PhiTB   = (uint4*)xDf;
  uint4* Wp      = (uint4*)(ws + 5*BL + 52428800 + 3*4915200);   // 13*18432
  char*  mbase   = ws + 5*BL + 52428800 + 3*4915200 + 13*18432;
  int*   pres    = (int*)(mbase);

  float* out0 = (float*)d_out;
  float* out1 = out0 + (size_t)NB*3*IMGSZ;

  // wide-parallel head; meta folded into pack_w with parallel loads
  ew_u<<<1200, 256, 0, stream>>>(x, xprev, t_p, u, 307200);
  pack_phib<<<384, 256, 0, stream>>>(PhiW, PhiB);
  pack_phitb<<<384, 256, 0, stream>>>(PhiTW, PhiTB);
  pack_w<<<13, 256, 0, stream>>>(c1f_w,c2f_w,c1b_w,c2b_w,c1g_w,c2g_w,conv3G,
                                 c1f_p,c2f_p,c1b_p,c2b_p,c1g_p,c2g_p,
                                 pres, Wp);

  // zeta path
  phi_gemm<<<dim3(25,4,3), 256, 0, stream>>>(u, PhiB, PhA);
  phit_gemm<<<dim3(25,4,3), 256, 0, stream>>>(PhA, PhiTB, u, PhiTb, lam, x_input);

  // x_D = conv_D(x_input): fused direct -> blocked bf16
  conv_direct_blocked<<<dim3(400,4,NB), 256, 0, stream>>>(x_input, convD, xDb);

  dim3 mg(10,40,NB);        // 8-row tiles
  dim3 mg2(10,40,NB*2);     // dual-job
  uint4* W_c1f = Wp + 0*1152;
  uint4* W_c2f = Wp + 1*1152;   // 3 classes
  uint4* W_c1b = Wp + 4*1152;
  uint4* W_c2b = Wp + 5*1152;   // 3 classes
  uint4* W_c1g = Wp + 8*1152;
  uint4* W_c2g = Wp + 9*1152;   // 3 classes
  uint4* W_g3  = Wp + 12*1152;

  // h1 = relu(adconv(x_D, c1f))
  mfma_conv_s<1,1,2,0,1,8><<<mg,256,0,stream>>>(xDb, W_c1f, Bb, nullptr,0, nullptr,nullptr,nullptr);
  // x_forward = adconv(h1, c2f)
  mfma_conv_s<3,3,2,0,0,8><<<mg,256,0,stream>>>(Bb, W_c2f, Cb, pres,1, nullptr,nullptr,nullptr);
  // h2 = relu(adconv(soft(x_forward), c1f)) -> Db ; h5 = relu(adconv(x_forward, c1b)) -> Bb
  mfma_conv_d<1,1,2,8, 2,1, 0,1><<<mg2,256,0,stream>>>(Cb, Cb, W_c1f, W_c1b, Db, Bb,
                                                       nullptr,0, sthr, nullptr,nullptr, nullptr);
  // relu(x_backward) -> Eb ; symloss = adconv(h5, c2b) - x_D -> out1
  mfma_conv_d<3,3,2,8, 0,1, 0,3><<<mg2,256,0,stream>>>(Db, Bb, W_c2b, W_c2b, Eb, out1,
                                                       pres,3, nullptr, nullptr, (const float*)xDb, nullptr);
  // relu(h3) = relu(adconv(relu_xb, c1g)) -> Db
  mfma_conv_s<1,1,2,0,1,8><<<mg,256,0,stream>>>(Eb, W_c1g, Db, nullptr,0, nullptr,nullptr,nullptr);
  // h4 = adconv(relu_h3, c2g)
  mfma_conv_s<3,3,2,0,0,8><<<mg,256,0,stream>>>(Db, W_c2g, Eb, pres,5, nullptr,nullptr,nullptr);
  // x_pred = x_input + ms * conv3_G(h4)  -> out0
  mfma_conv_s<1,1,1,0,2,8><<<mg,256,0,stream>>>(Eb, W_g3, out0, nullptr,0, nullptr, x_input, mrg);
}